// Round 1
// baseline (234.096 us; speedup 1.0000x reference)
//
#include <hip/hip_runtime.h>

#define N_NODES 20000
#define N_EDGES 320000
#define NEGF   -1e30f

// d_out layout (floats):
//   out0    : [0,              N*64)
//   out1    : [N*64,           N*64 + N*192)
//   logits  : [N*256,          N*256 + E*8)

__global__ __launch_bounds__(256) void k_logits(
    const float* __restrict__ k0, const float* __restrict__ k1,
    const float* __restrict__ q0, const float* __restrict__ q1,
    const int* __restrict__ dst, float* __restrict__ logits,
    int* __restrict__ counts)
{
    int t = blockIdx.x * 256 + threadIdx.x;          // t in [0, E*H)
    if (t >= N_EDGES * 8) return;
    int e = t >> 3, h = t & 7;
    int d = dst[e];

    const float4* k0v = (const float4*)(k0 + (size_t)e * 64  + h * 8);
    const float4* q0v = (const float4*)(q0 + (size_t)d * 64  + h * 8);
    const float4* k1v = (const float4*)(k1 + (size_t)e * 192 + h * 24);
    const float4* q1v = (const float4*)(q1 + (size_t)d * 192 + h * 24);

    float s = 0.f;
#pragma unroll
    for (int i = 0; i < 2; ++i) {
        float4 a = k0v[i], b = q0v[i];
        s += a.x * b.x + a.y * b.y + a.z * b.z + a.w * b.w;
    }
#pragma unroll
    for (int i = 0; i < 6; ++i) {
        float4 a = k1v[i], b = q1v[i];
        s += a.x * b.x + a.y * b.y + a.z * b.z + a.w * b.w;
    }
    logits[t] = s * 0.0625f;                         // 1/sqrt(256)
    if (h == 0) atomicAdd(&counts[d], 1);
}

__global__ __launch_bounds__(256) void k_scan_part(
    const int* __restrict__ counts, int* __restrict__ partial)
{
    __shared__ int sm[256];
    int n = blockIdx.x * 256 + threadIdx.x;
    int v = (n < N_NODES) ? counts[n] : 0;
    sm[threadIdx.x] = v; __syncthreads();
    for (int off = 128; off > 0; off >>= 1) {
        if (threadIdx.x < off) sm[threadIdx.x] += sm[threadIdx.x + off];
        __syncthreads();
    }
    if (threadIdx.x == 0) partial[blockIdx.x] = sm[0];
}

__global__ void k_scan_small(int* partial, int nb)
{
    if (blockIdx.x == 0 && threadIdx.x == 0) {
        int run = 0;
        for (int i = 0; i < nb; ++i) { int v = partial[i]; partial[i] = run; run += v; }
    }
}

__global__ __launch_bounds__(256) void k_scan_final(
    const int* __restrict__ counts, const int* __restrict__ partial,
    int* __restrict__ offsets, int* __restrict__ cursor)
{
    __shared__ int sm[256];
    int n = blockIdx.x * 256 + threadIdx.x;
    int v = (n < N_NODES) ? counts[n] : 0;
    sm[threadIdx.x] = v; __syncthreads();
    // Hillis-Steele inclusive scan (read-all / barrier / write-all / barrier)
    for (int off = 1; off < 256; off <<= 1) {
        int x = (threadIdx.x >= off) ? sm[threadIdx.x - off] : 0;
        __syncthreads();
        sm[threadIdx.x] += x;
        __syncthreads();
    }
    int excl = sm[threadIdx.x] - v + partial[blockIdx.x];
    if (n < N_NODES) { offsets[n] = excl; cursor[n] = excl; }
    if (n == 0) offsets[N_NODES] = N_EDGES;
}

__global__ __launch_bounds__(256) void k_fill(
    const int* __restrict__ dst, int* __restrict__ cursor, int* __restrict__ bucket)
{
    int e = blockIdx.x * 256 + threadIdx.x;
    if (e >= N_EDGES) return;
    int d = dst[e];
    int pos = atomicAdd(&cursor[d], 1);
    bucket[pos] = e;
}

__global__ __launch_bounds__(256) void k_agg(
    const float* __restrict__ v0, const float* __restrict__ v1,
    const float* __restrict__ logits, const int* __restrict__ offsets,
    const int* __restrict__ bucket,
    float* __restrict__ out0, float* __restrict__ out1)
{
    int wave = blockIdx.x * 4 + (threadIdx.x >> 6);   // one wave per node
    int l = threadIdx.x & 63;
    if (wave >= N_NODES) return;
    int n = wave;
    int rs = offsets[n], re = offsets[n + 1];
    int h = l & 7;

    // ---- pass A: online softmax stats; lane handles head (l&7), edge slot (l>>3)
    float M = NEGF, S = 0.f;
    for (int base = rs; base < re; base += 8) {
        int ei = base + (l >> 3);
        float x = NEGF;
        if (ei < re) {
            int e = bucket[ei];
            x = logits[(size_t)e * 8 + h];
        }
        float Mn = fmaxf(M, x);
        S = S * __expf(M - Mn) + ((x > NEGF) ? __expf(x - Mn) : 0.f);
        M = Mn;
    }
    // combine the 8 edge-slots per head (lanes differing in bits 3..5)
    for (int mask = 8; mask < 64; mask <<= 1) {
        float Mo = __shfl_xor(M, mask);
        float So = __shfl_xor(S, mask);
        float Mn = fmaxf(M, Mo);
        S = S * __expf(M - Mn) + So * __expf(Mo - Mn);
        M = Mn;
    }
    float rinv = (S > 0.f) ? 1.f / S : 0.f;

    // ---- pass B: weighted aggregation
    float acc0 = 0.f, acc1a = 0.f, acc1b = 0.f, acc1c = 0.f;
    int h0 = l >> 3;           // head of out0 position l (channel l)
    int ha = l / 24;           // head of out1 flat position l
    int hb = (64 + l) / 24;    // head of out1 flat position 64+l
    int hc = (128 + l) / 24;   // head of out1 flat position 128+l
    for (int idx = rs; idx < re; ++idx) {
        int e = bucket[idx];                       // uniform across wave
        float x = logits[(size_t)e * 8 + h];
        float am = __expf(x - M) * rinv;           // alpha for head l&7
        float a0 = __shfl(am, h0);
        float aa = __shfl(am, ha);
        float ab = __shfl(am, hb);
        float ac = __shfl(am, hc);
        size_t b0 = (size_t)e * 64;
        size_t b1 = (size_t)e * 192;
        acc0  += a0 * v0[b0 + l];
        acc1a += aa * v1[b1 + l];
        acc1b += ab * v1[b1 + 64 + l];
        acc1c += ac * v1[b1 + 128 + l];
    }
    out0[(size_t)n * 64 + l] = acc0;
    float* o1 = out1 + (size_t)n * 192;
    o1[l] = acc1a; o1[64 + l] = acc1b; o1[128 + l] = acc1c;
}

extern "C" void kernel_launch(void* const* d_in, const int* in_sizes, int n_in,
                              void* d_out, int out_size, void* d_ws, size_t ws_size,
                              hipStream_t stream) {
    const float* v0 = (const float*)d_in[0];
    const float* v1 = (const float*)d_in[1];
    const float* k0 = (const float*)d_in[2];
    const float* k1 = (const float*)d_in[3];
    const float* q0 = (const float*)d_in[4];
    const float* q1 = (const float*)d_in[5];
    const int*  dst = (const int*)d_in[6];

    float* out0   = (float*)d_out;
    float* out1   = out0 + (size_t)N_NODES * 64;
    float* logits = out1 + (size_t)N_NODES * 192;

    int* wsI     = (int*)d_ws;
    int* counts  = wsI;             // N
    int* offsets = wsI + 20000;     // N+1
    int* cursor  = wsI + 40064;     // N
    int* partial = wsI + 60064;     // 128
    int* bucket  = wsI + 60192;     // E
    // total ws use: ~1.52 MB

    hipMemsetAsync(counts, 0, N_NODES * sizeof(int), stream);
    k_logits    <<<10000, 256, 0, stream>>>(k0, k1, q0, q1, dst, logits, counts);
    k_scan_part <<<79,    256, 0, stream>>>(counts, partial);
    k_scan_small<<<1,      64, 0, stream>>>(partial, 79);
    k_scan_final<<<79,    256, 0, stream>>>(counts, partial, offsets, cursor);
    k_fill      <<<1250,  256, 0, stream>>>(dst, cursor, bucket);
    k_agg       <<<5000,  256, 0, stream>>>(v0, v1, logits, offsets, bucket, out0, out1);
}

// Round 2
// 227.614 us; speedup vs baseline: 1.0285x; 1.0285x over previous
//
#include <hip/hip_runtime.h>

#define N_NODES 20000
#define N_EDGES 320000
#define NEGF   -1e30f

// d_out layout (floats):
//   out0    : [0,              N*64)
//   out1    : [N*64,           N*64 + N*192)
//   logits  : [N*256,          N*256 + E*8)

__global__ __launch_bounds__(256) void k_zero(int* __restrict__ counts)
{
    int n = blockIdx.x * 256 + threadIdx.x;
    if (n < N_NODES) counts[n] = 0;
}

__global__ __launch_bounds__(256) void k_logits(
    const float* __restrict__ k0, const float* __restrict__ k1,
    const float* __restrict__ q0, const float* __restrict__ q1,
    const int* __restrict__ dst, float* __restrict__ logits,
    int* __restrict__ counts)
{
    int t = blockIdx.x * 256 + threadIdx.x;          // t in [0, E*H)
    if (t >= N_EDGES * 8) return;
    int e = t >> 3, h = t & 7;
    int d = dst[e];

    const float4* k0v = (const float4*)(k0 + (size_t)e * 64  + h * 8);
    const float4* q0v = (const float4*)(q0 + (size_t)d * 64  + h * 8);
    const float4* k1v = (const float4*)(k1 + (size_t)e * 192 + h * 24);
    const float4* q1v = (const float4*)(q1 + (size_t)d * 192 + h * 24);

    float s = 0.f;
#pragma unroll
    for (int i = 0; i < 2; ++i) {
        float4 a = k0v[i], b = q0v[i];
        s += a.x * b.x + a.y * b.y + a.z * b.z + a.w * b.w;
    }
#pragma unroll
    for (int i = 0; i < 6; ++i) {
        float4 a = k1v[i], b = q1v[i];
        s += a.x * b.x + a.y * b.y + a.z * b.z + a.w * b.w;
    }
    logits[t] = s * 0.0625f;                         // 1/sqrt(256)
    if (h == 0) atomicAdd(&counts[d], 1);
}

// Single-block scan: 1024 threads, 20 nodes per thread (1000 active), LDS scan.
__global__ __launch_bounds__(1024) void k_scan(
    const int* __restrict__ counts, int* __restrict__ offsets,
    int* __restrict__ cursor)
{
    __shared__ int sm[1024];
    int t = threadIdx.x;
    int base = t * 20;
    int local[20];
    int s = 0;
    if (base < N_NODES) {
#pragma unroll
        for (int i = 0; i < 20; ++i) { local[i] = counts[base + i]; s += local[i]; }
    }
    sm[t] = s; __syncthreads();
    for (int off = 1; off < 1024; off <<= 1) {
        int x = (t >= off) ? sm[t - off] : 0;
        __syncthreads();
        sm[t] += x;
        __syncthreads();
    }
    int run = sm[t] - s;                 // exclusive prefix
    if (base < N_NODES) {
#pragma unroll
        for (int i = 0; i < 20; ++i) {
            offsets[base + i] = run; cursor[base + i] = run; run += local[i];
        }
    }
    if (t == 0) offsets[N_NODES] = N_EDGES;
}

__global__ __launch_bounds__(256) void k_fill(
    const int* __restrict__ dst, int* __restrict__ cursor, int* __restrict__ bucket)
{
    int e = blockIdx.x * 256 + threadIdx.x;
    if (e >= N_EDGES) return;
    int d = dst[e];
    int pos = atomicAdd(&cursor[d], 1);
    bucket[pos] = e;
}

__global__ __launch_bounds__(256) void k_agg(
    const float* __restrict__ v0, const float* __restrict__ v1,
    const float* __restrict__ logits, const int* __restrict__ offsets,
    const int* __restrict__ bucket,
    float* __restrict__ out0, float* __restrict__ out1)
{
    int wave = blockIdx.x * 4 + (threadIdx.x >> 6);   // one wave per node
    int l = threadIdx.x & 63;
    if (wave >= N_NODES) return;
    int n = wave;
    int rs = offsets[n], re = offsets[n + 1];
    int h = l & 7;

    // ---- pass A: online softmax stats; lane handles head (l&7), edge slot (l>>3)
    float M = NEGF, S = 0.f;
    for (int base = rs; base < re; base += 8) {
        int ei = base + (l >> 3);
        float x = NEGF;
        if (ei < re) {
            int e = bucket[ei];
            x = logits[(size_t)e * 8 + h];
        }
        float Mn = fmaxf(M, x);
        S = S * __expf(M - Mn) + ((x > NEGF) ? __expf(x - Mn) : 0.f);
        M = Mn;
    }
    // combine the 8 edge-slots per head (lanes differing in bits 3..5)
    for (int mask = 8; mask < 64; mask <<= 1) {
        float Mo = __shfl_xor(M, mask);
        float So = __shfl_xor(S, mask);
        float Mn = fmaxf(M, Mo);
        S = S * __expf(M - Mn) + So * __expf(Mo - Mn);
        M = Mn;
    }
    float rinv = (S > 0.f) ? 1.f / S : 0.f;

    // ---- pass B: weighted aggregation
    float acc0 = 0.f, acc1a = 0.f, acc1b = 0.f, acc1c = 0.f;
    int h0 = l >> 3;           // head of out0 position l (channel l)
    int ha = l / 24;           // head of out1 flat position l
    int hb = (64 + l) / 24;    // head of out1 flat position 64+l
    int hc = (128 + l) / 24;   // head of out1 flat position 128+l
    for (int idx = rs; idx < re; ++idx) {
        int e = bucket[idx];                       // uniform across wave
        float x = logits[(size_t)e * 8 + h];
        float am = __expf(x - M) * rinv;           // alpha for head l&7
        float a0 = __shfl(am, h0);
        float aa = __shfl(am, ha);
        float ab = __shfl(am, hb);
        float ac = __shfl(am, hc);
        size_t b0 = (size_t)e * 64;
        size_t b1 = (size_t)e * 192;
        acc0  += a0 * v0[b0 + l];
        acc1a += aa * v1[b1 + l];
        acc1b += ab * v1[b1 + 64 + l];
        acc1c += ac * v1[b1 + 128 + l];
    }
    out0[(size_t)n * 64 + l] = acc0;
    float* o1 = out1 + (size_t)n * 192;
    o1[l] = acc1a; o1[64 + l] = acc1b; o1[128 + l] = acc1c;
}

extern "C" void kernel_launch(void* const* d_in, const int* in_sizes, int n_in,
                              void* d_out, int out_size, void* d_ws, size_t ws_size,
                              hipStream_t stream) {
    const float* v0 = (const float*)d_in[0];
    const float* v1 = (const float*)d_in[1];
    const float* k0 = (const float*)d_in[2];
    const float* k1 = (const float*)d_in[3];
    const float* q0 = (const float*)d_in[4];
    const float* q1 = (const float*)d_in[5];
    const int*  dst = (const int*)d_in[6];

    float* out0   = (float*)d_out;
    float* out1   = out0 + (size_t)N_NODES * 64;
    float* logits = out1 + (size_t)N_NODES * 192;

    int* wsI     = (int*)d_ws;
    int* counts  = wsI;             // N
    int* offsets = wsI + 20000;     // N+1
    int* cursor  = wsI + 40064;     // N
    int* bucket  = wsI + 60192;     // E
    // total ws use: ~1.52 MB

    k_zero   <<<79,    256,  0, stream>>>(counts);
    k_logits <<<10000, 256,  0, stream>>>(k0, k1, q0, q1, dst, logits, counts);
    k_scan   <<<1,     1024, 0, stream>>>(counts, offsets, cursor);
    k_fill   <<<1250,  256,  0, stream>>>(dst, cursor, bucket);
    k_agg    <<<5000,  256,  0, stream>>>(v0, v1, logits, offsets, bucket, out0, out1);
}

// Round 3
// 217.108 us; speedup vs baseline: 1.0782x; 1.0484x over previous
//
#include <hip/hip_runtime.h>

#define N_NODES 20000
#define N_EDGES 320000
#define NEGF   -1e30f

// d_out layout (floats):
//   out0    : [0,              N*64)
//   out1    : [N*64,           N*64 + N*192)
//   logits  : [N*256,          N*256 + E*8)

__global__ __launch_bounds__(256) void k_zero(int* __restrict__ counts)
{
    int n = blockIdx.x * 256 + threadIdx.x;
    if (n < N_NODES) counts[n] = 0;
}

__global__ __launch_bounds__(256) void k_count(
    const int* __restrict__ dst, int* __restrict__ counts)
{
    int e = blockIdx.x * 256 + threadIdx.x;
    if (e < N_EDGES) atomicAdd(&counts[dst[e]], 1);
}

// Single-block scan: 1024 threads, 20 nodes per thread, LDS Hillis-Steele.
__global__ __launch_bounds__(1024) void k_scan(
    const int* __restrict__ counts, int* __restrict__ offsets,
    int* __restrict__ cursor)
{
    __shared__ int sm[1024];
    int t = threadIdx.x;
    int base = t * 20;
    int local[20];
    int s = 0;
    if (base < N_NODES) {
#pragma unroll
        for (int i = 0; i < 20; ++i) { local[i] = counts[base + i]; s += local[i]; }
    }
    sm[t] = s; __syncthreads();
    for (int off = 1; off < 1024; off <<= 1) {
        int x = (t >= off) ? sm[t - off] : 0;
        __syncthreads();
        sm[t] += x;
        __syncthreads();
    }
    int run = sm[t] - s;                 // exclusive prefix
    if (base < N_NODES) {
#pragma unroll
        for (int i = 0; i < 20; ++i) {
            offsets[base + i] = run; cursor[base + i] = run; run += local[i];
        }
    }
    if (t == 0) offsets[N_NODES] = N_EDGES;
}

// logits + CSR bucket fill fused (cursor is ready before this launches)
__global__ __launch_bounds__(256) void k_logits(
    const float* __restrict__ k0, const float* __restrict__ k1,
    const float* __restrict__ q0, const float* __restrict__ q1,
    const int* __restrict__ dst, float* __restrict__ logits,
    int* __restrict__ cursor, int* __restrict__ bucket)
{
    int t = blockIdx.x * 256 + threadIdx.x;          // t in [0, E*H)
    if (t >= N_EDGES * 8) return;
    int e = t >> 3, h = t & 7;
    int d = dst[e];

    const float4* k0v = (const float4*)(k0 + (size_t)e * 64  + h * 8);
    const float4* q0v = (const float4*)(q0 + (size_t)d * 64  + h * 8);
    const float4* k1v = (const float4*)(k1 + (size_t)e * 192 + h * 24);
    const float4* q1v = (const float4*)(q1 + (size_t)d * 192 + h * 24);

    float s = 0.f;
#pragma unroll
    for (int i = 0; i < 2; ++i) {
        float4 a = k0v[i], b = q0v[i];
        s += a.x * b.x + a.y * b.y + a.z * b.z + a.w * b.w;
    }
#pragma unroll
    for (int i = 0; i < 6; ++i) {
        float4 a = k1v[i], b = q1v[i];
        s += a.x * b.x + a.y * b.y + a.z * b.z + a.w * b.w;
    }
    logits[t] = s * 0.0625f;                         // 1/sqrt(256)
    if (h == 0) {
        int pos = atomicAdd(&cursor[d], 1);
        bucket[pos] = e;
    }
}

__global__ __launch_bounds__(256) void k_agg(
    const float* __restrict__ v0, const float* __restrict__ v1,
    const float* __restrict__ logits, const int* __restrict__ offsets,
    const int* __restrict__ bucket,
    float* __restrict__ out0, float* __restrict__ out1)
{
    __shared__ float xb[4][512];                      // per-wave: 64 slots x 8 heads
    int w = threadIdx.x >> 6;
    int l = threadIdx.x & 63;
    int node = blockIdx.x * 4 + w;
    if (node >= N_NODES) return;
    float* X = xb[w];

    int rs = offsets[node], re = offsets[node + 1];
    int deg = re - rs;
    int h = l & 7, slot8 = l >> 3;

    // ---- pass A: online softmax stats; stash logits in LDS (slots < 64)
    float M = NEGF, S = 0.f;
    for (int base = 0; base < deg; base += 8) {
        int s = base + slot8;
        float x = NEGF;
        if (s < deg) {
            int e = bucket[rs + s];
            x = logits[(size_t)e * 8 + h];
            if (s < 64) X[s * 8 + h] = x;
        }
        float Mn = fmaxf(M, x);
        S = S * __expf(M - Mn) + ((s < deg) ? __expf(x - Mn) : 0.f);
        M = Mn;
    }
    for (int mask = 8; mask < 64; mask <<= 1) {
        float Mo = __shfl_xor(M, mask);
        float So = __shfl_xor(S, mask);
        float Mn = fmaxf(M, Mo);
        S = S * __expf(M - Mn) + So * __expf(Mo - Mn);
        M = Mn;
    }
    float rinv = (S > 0.f) ? 1.f / S : 0.f;

    // ---- convert stashed logits to alphas in LDS (same lane layout)
    int degc = deg < 64 ? deg : 64;
    for (int base = 0; base < degc; base += 8) {
        int s = base + slot8;
        if (s < degc) X[s * 8 + h] = __expf(X[s * 8 + h] - M) * rinv;
    }

    // ---- pass B: 4 edges per iteration, float4 value loads
    int s2 = l >> 4;                   // edge slot within group of 4
    int c  = l & 15;                   // float4 lane within a row
    int hv0  = c >> 1;                 // head of v0 float4 (channels 4c..4c+3)
    int hv1a = c / 6;                  // head of v1 float4 index c
    int hv1b = (c + 16) / 6;           // head of v1 float4 index c+16
    int hv1c = (c + 32) / 6;           // head of v1 float4 index c+32
    // M/rinv for those heads (lane h holds head h's stats)
    float M0 = __shfl(M, hv0),  R0 = __shfl(rinv, hv0);
    float Ma = __shfl(M, hv1a), Ra = __shfl(rinv, hv1a);
    float Mb = __shfl(M, hv1b), Rb = __shfl(rinv, hv1b);
    float Mc = __shfl(M, hv1c), Rc = __shfl(rinv, hv1c);

    float4 a0  = {0,0,0,0}, a1a = {0,0,0,0}, a1b = {0,0,0,0}, a1c = {0,0,0,0};
    for (int base = 0; base < deg; base += 4) {
        int s = base + s2;
        bool ok = s < deg;
        int e = bucket[rs + (ok ? s : deg - 1)];
        float al0, ala, alb, alc;
        if (s < 64) {
            al0 = X[s * 8 + hv0];
            ala = X[s * 8 + hv1a];
            alb = X[s * 8 + hv1b];
            alc = X[s * 8 + hv1c];
        } else {
            const float* lr = logits + (size_t)e * 8;
            al0 = __expf(lr[hv0]  - M0) * R0;
            ala = __expf(lr[hv1a] - Ma) * Ra;
            alb = __expf(lr[hv1b] - Mb) * Rb;
            alc = __expf(lr[hv1c] - Mc) * Rc;
        }
        if (!ok) { al0 = ala = alb = alc = 0.f; }
        const float4* r0 = (const float4*)(v0 + (size_t)e * 64);
        const float4* r1 = (const float4*)(v1 + (size_t)e * 192);
        float4 p0 = r0[c];
        float4 pa = r1[c];
        float4 pb = r1[c + 16];
        float4 pc = r1[c + 32];
        a0.x  += al0 * p0.x; a0.y  += al0 * p0.y; a0.z  += al0 * p0.z; a0.w  += al0 * p0.w;
        a1a.x += ala * pa.x; a1a.y += ala * pa.y; a1a.z += ala * pa.z; a1a.w += ala * pa.w;
        a1b.x += alb * pb.x; a1b.y += alb * pb.y; a1b.z += alb * pb.z; a1b.w += alb * pb.w;
        a1c.x += alc * pc.x; a1c.y += alc * pc.y; a1c.z += alc * pc.z; a1c.w += alc * pc.w;
    }
    // reduce across the 4 edge slots (lanes differing in bits 4..5)
#pragma unroll
    for (int mask = 16; mask < 64; mask <<= 1) {
        a0.x  += __shfl_xor(a0.x,  mask); a0.y  += __shfl_xor(a0.y,  mask);
        a0.z  += __shfl_xor(a0.z,  mask); a0.w  += __shfl_xor(a0.w,  mask);
        a1a.x += __shfl_xor(a1a.x, mask); a1a.y += __shfl_xor(a1a.y, mask);
        a1a.z += __shfl_xor(a1a.z, mask); a1a.w += __shfl_xor(a1a.w, mask);
        a1b.x += __shfl_xor(a1b.x, mask); a1b.y += __shfl_xor(a1b.y, mask);
        a1b.z += __shfl_xor(a1b.z, mask); a1b.w += __shfl_xor(a1b.w, mask);
        a1c.x += __shfl_xor(a1c.x, mask); a1c.y += __shfl_xor(a1c.y, mask);
        a1c.z += __shfl_xor(a1c.z, mask); a1c.w += __shfl_xor(a1c.w, mask);
    }
    if (l < 16) {
        float4* o0 = (float4*)(out0 + (size_t)node * 64);
        float4* o1 = (float4*)(out1 + (size_t)node * 192);
        o0[c]      = a0;
        o1[c]      = a1a;
        o1[c + 16] = a1b;
        o1[c + 32] = a1c;
    }
}

extern "C" void kernel_launch(void* const* d_in, const int* in_sizes, int n_in,
                              void* d_out, int out_size, void* d_ws, size_t ws_size,
                              hipStream_t stream) {
    const float* v0 = (const float*)d_in[0];
    const float* v1 = (const float*)d_in[1];
    const float* k0 = (const float*)d_in[2];
    const float* k1 = (const float*)d_in[3];
    const float* q0 = (const float*)d_in[4];
    const float* q1 = (const float*)d_in[5];
    const int*  dst = (const int*)d_in[6];

    float* out0   = (float*)d_out;
    float* out1   = out0 + (size_t)N_NODES * 64;
    float* logits = out1 + (size_t)N_NODES * 192;

    int* wsI     = (int*)d_ws;
    int* counts  = wsI;             // N
    int* offsets = wsI + 20000;     // N+1
    int* cursor  = wsI + 40064;     // N
    int* bucket  = wsI + 60192;     // E

    k_zero   <<<79,    256,  0, stream>>>(counts);
    k_count  <<<1250,  256,  0, stream>>>(dst, counts);
    k_scan   <<<1,     1024, 0, stream>>>(counts, offsets, cursor);
    k_logits <<<10000, 256,  0, stream>>>(k0, k1, q0, q1, dst, logits, cursor, bucket);
    k_agg    <<<5000,  256,  0, stream>>>(v0, v1, logits, offsets, bucket, out0, out1);
}

// Round 4
// 204.226 us; speedup vs baseline: 1.1463x; 1.0631x over previous
//
#include <hip/hip_runtime.h>

#define N_NODES 20000
#define N_EDGES 320000
#define NEGF   -1e30f

// d_out layout (floats):
//   out0    : [0,              N*64)
//   out1    : [N*64,           N*64 + N*192)
//   logits  : [N*256,          N*256 + E*8)

__global__ __launch_bounds__(256) void k_zero(int* __restrict__ counts)
{
    int n = blockIdx.x * 256 + threadIdx.x;
    if (n < N_NODES) counts[n] = 0;
}

__global__ __launch_bounds__(256) void k_count(
    const int* __restrict__ dst, int* __restrict__ counts)
{
    int e = blockIdx.x * 256 + threadIdx.x;
    if (e < N_EDGES) atomicAdd(&counts[dst[e]], 1);
}

// Single-block scan: 1024 threads, 20 nodes per thread, LDS Hillis-Steele.
__global__ __launch_bounds__(1024) void k_scan(
    const int* __restrict__ counts, int* __restrict__ offsets,
    int* __restrict__ cursor)
{
    __shared__ int sm[1024];
    int t = threadIdx.x;
    int base = t * 20;
    int local[20];
    int s = 0;
    if (base < N_NODES) {
#pragma unroll
        for (int i = 0; i < 20; ++i) { local[i] = counts[base + i]; s += local[i]; }
    }
    sm[t] = s; __syncthreads();
    for (int off = 1; off < 1024; off <<= 1) {
        int x = (t >= off) ? sm[t - off] : 0;
        __syncthreads();
        sm[t] += x;
        __syncthreads();
    }
    int run = sm[t] - s;                 // exclusive prefix
    if (base < N_NODES) {
#pragma unroll
        for (int i = 0; i < 20; ++i) {
            offsets[base + i] = run; cursor[base + i] = run; run += local[i];
        }
    }
    if (t == 0) offsets[N_NODES] = N_EDGES;
}

__global__ __launch_bounds__(256) void k_fill(
    const int* __restrict__ dst, int* __restrict__ cursor, int* __restrict__ bucket)
{
    int e = blockIdx.x * 256 + threadIdx.x;
    if (e >= N_EDGES) return;
    int d = dst[e];
    int pos = atomicAdd(&cursor[d], 1);
    bucket[pos] = e;
}

// One wave per node: q staged in LDS once; stream k rows -> logits + online
// softmax; alphas in LDS; then weighted aggregation of v rows. Fully fused.
__global__ __launch_bounds__(256) void k_fused(
    const float* __restrict__ v0, const float* __restrict__ v1,
    const float* __restrict__ k0, const float* __restrict__ k1,
    const float* __restrict__ q0, const float* __restrict__ q1,
    const int* __restrict__ offsets, const int* __restrict__ bucket,
    float* __restrict__ logits, float* __restrict__ out0, float* __restrict__ out1)
{
    __shared__ float xb[4][512];     // per-wave: 64 slots x 8 heads (logits->alphas)
    __shared__ float qs[4][256];     // per-wave: q row (64 deg0 + 192 deg1)
    int w = threadIdx.x >> 6;
    int l = threadIdx.x & 63;
    int node = blockIdx.x * 4 + w;   // grid covers exactly N_NODES waves
    float* X = xb[w];
    float* Q = qs[w];

    int rs = offsets[node], re = offsets[node + 1];
    int deg = re - rs;
    int h = l & 7, slot8 = l >> 3;

    // ---- stage q row into LDS (1 float4 per lane)
    {
        float4* Qv = (float4*)Q;
        if (l < 16) Qv[l] = ((const float4*)(q0 + (size_t)node * 64))[l];
        else        Qv[l] = ((const float4*)(q1 + (size_t)node * 192))[l - 16];
    }
    __syncthreads();

    // ---- pass A: logits + online softmax; 8 edges/iter, lane=(slot,head)
    const float4* Qh0 = (const float4*)(Q + h * 8);        // 2 float4
    const float4* Qh1 = (const float4*)(Q + 64 + h * 24);  // 6 float4
    float M = NEGF, S = 0.f;
    for (int base = 0; base < deg; base += 8) {
        int s = base + slot8;
        bool ok = s < deg;
        float x = NEGF;
        if (ok) {
            int e = bucket[rs + s];
            const float4* kk0 = (const float4*)(k0 + (size_t)e * 64  + h * 8);
            const float4* kk1 = (const float4*)(k1 + (size_t)e * 192 + h * 24);
            float acc = 0.f;
#pragma unroll
            for (int i = 0; i < 2; ++i) {
                float4 a = kk0[i], b = Qh0[i];
                acc += a.x * b.x + a.y * b.y + a.z * b.z + a.w * b.w;
            }
#pragma unroll
            for (int i = 0; i < 6; ++i) {
                float4 a = kk1[i], b = Qh1[i];
                acc += a.x * b.x + a.y * b.y + a.z * b.z + a.w * b.w;
            }
            x = acc * 0.0625f;                       // 1/sqrt(256)
            logits[(size_t)e * 8 + h] = x;           // prelogits output
            if (s < 64) X[s * 8 + h] = x;
        }
        float Mn = fmaxf(M, x);
        S = S * __expf(M - Mn) + (ok ? __expf(x - Mn) : 0.f);
        M = Mn;
    }
    // combine the 8 edge-slots per head (lanes differing in bits 3..5)
    for (int mask = 8; mask < 64; mask <<= 1) {
        float Mo = __shfl_xor(M, mask);
        float So = __shfl_xor(S, mask);
        float Mn = fmaxf(M, Mo);
        S = S * __expf(M - Mn) + So * __expf(Mo - Mn);
        M = Mn;
    }
    float rinv = (S > 0.f) ? 1.f / S : 0.f;

    // ---- convert stashed logits to alphas in LDS (same lane mapping as writer)
    int degc = deg < 64 ? deg : 64;
    for (int base = 0; base < degc; base += 8) {
        int s = base + slot8;
        if (s < degc) X[s * 8 + h] = __expf(X[s * 8 + h] - M) * rinv;
    }
    __syncthreads();

    // ---- pass B: 4 edges per iteration, float4 value loads
    int s2 = l >> 4;                   // edge slot within group of 4
    int c  = l & 15;                   // float4 lane within a row
    int hv0  = c >> 1;                 // head of v0 float4 c
    int hv1a = c / 6;                  // head of v1 float4 c
    int hv1b = (c + 16) / 6;           // head of v1 float4 c+16
    int hv1c = (c + 32) / 6;           // head of v1 float4 c+32
    float M0 = __shfl(M, hv0),  R0 = __shfl(rinv, hv0);
    float Ma = __shfl(M, hv1a), Ra = __shfl(rinv, hv1a);
    float Mb = __shfl(M, hv1b), Rb = __shfl(rinv, hv1b);
    float Mc = __shfl(M, hv1c), Rc = __shfl(rinv, hv1c);

    float4 a0  = {0,0,0,0}, a1a = {0,0,0,0}, a1b = {0,0,0,0}, a1c = {0,0,0,0};
    for (int base = 0; base < deg; base += 4) {
        int s = base + s2;
        bool ok = s < deg;
        int e = bucket[rs + (ok ? s : deg - 1)];
        float al0, ala, alb, alc;
        if (s < 64) {
            al0 = X[s * 8 + hv0];
            ala = X[s * 8 + hv1a];
            alb = X[s * 8 + hv1b];
            alc = X[s * 8 + hv1c];
        } else {
            const float* lr = logits + (size_t)e * 8;
            al0 = __expf(lr[hv0]  - M0) * R0;
            ala = __expf(lr[hv1a] - Ma) * Ra;
            alb = __expf(lr[hv1b] - Mb) * Rb;
            alc = __expf(lr[hv1c] - Mc) * Rc;
        }
        if (!ok) { al0 = ala = alb = alc = 0.f; }
        const float4* r0 = (const float4*)(v0 + (size_t)e * 64);
        const float4* r1 = (const float4*)(v1 + (size_t)e * 192);
        float4 p0 = r0[c];
        float4 pa = r1[c];
        float4 pb = r1[c + 16];
        float4 pc = r1[c + 32];
        a0.x  += al0 * p0.x; a0.y  += al0 * p0.y; a0.z  += al0 * p0.z; a0.w  += al0 * p0.w;
        a1a.x += ala * pa.x; a1a.y += ala * pa.y; a1a.z += ala * pa.z; a1a.w += ala * pa.w;
        a1b.x += alb * pb.x; a1b.y += alb * pb.y; a1b.z += alb * pb.z; a1b.w += alb * pb.w;
        a1c.x += alc * pc.x; a1c.y += alc * pc.y; a1c.z += alc * pc.z; a1c.w += alc * pc.w;
    }
    // reduce across the 4 edge slots (lanes differing in bits 4..5)
#pragma unroll
    for (int mask = 16; mask < 64; mask <<= 1) {
        a0.x  += __shfl_xor(a0.x,  mask); a0.y  += __shfl_xor(a0.y,  mask);
        a0.z  += __shfl_xor(a0.z,  mask); a0.w  += __shfl_xor(a0.w,  mask);
        a1a.x += __shfl_xor(a1a.x, mask); a1a.y += __shfl_xor(a1a.y, mask);
        a1a.z += __shfl_xor(a1a.z, mask); a1a.w += __shfl_xor(a1a.w, mask);
        a1b.x += __shfl_xor(a1b.x, mask); a1b.y += __shfl_xor(a1b.y, mask);
        a1b.z += __shfl_xor(a1b.z, mask); a1b.w += __shfl_xor(a1b.w, mask);
        a1c.x += __shfl_xor(a1c.x, mask); a1c.y += __shfl_xor(a1c.y, mask);
        a1c.z += __shfl_xor(a1c.z, mask); a1c.w += __shfl_xor(a1c.w, mask);
    }
    if (l < 16) {
        float4* o0 = (float4*)(out0 + (size_t)node * 64);
        float4* o1 = (float4*)(out1 + (size_t)node * 192);
        o0[c]      = a0;
        o1[c]      = a1a;
        o1[c + 16] = a1b;
        o1[c + 32] = a1c;
    }
}

extern "C" void kernel_launch(void* const* d_in, const int* in_sizes, int n_in,
                              void* d_out, int out_size, void* d_ws, size_t ws_size,
                              hipStream_t stream) {
    const float* v0 = (const float*)d_in[0];
    const float* v1 = (const float*)d_in[1];
    const float* k0 = (const float*)d_in[2];
    const float* k1 = (const float*)d_in[3];
    const float* q0 = (const float*)d_in[4];
    const float* q1 = (const float*)d_in[5];
    const int*  dst = (const int*)d_in[6];

    float* out0   = (float*)d_out;
    float* out1   = out0 + (size_t)N_NODES * 64;
    float* logits = out1 + (size_t)N_NODES * 192;

    int* wsI     = (int*)d_ws;
    int* counts  = wsI;             // N
    int* offsets = wsI + 20000;     // N+1
    int* cursor  = wsI + 40064;     // N
    int* bucket  = wsI + 60192;     // E

    k_zero  <<<79,    256,  0, stream>>>(counts);
    k_count <<<1250,  256,  0, stream>>>(dst, counts);
    k_scan  <<<1,     1024, 0, stream>>>(counts, offsets, cursor);
    k_fill  <<<1250,  256,  0, stream>>>(dst, cursor, bucket);
    k_fused <<<5000,  256,  0, stream>>>(v0, v1, k0, k1, q0, q1,
                                         offsets, bucket, logits, out0, out1);
}

// Round 5
// 203.723 us; speedup vs baseline: 1.1491x; 1.0025x over previous
//
#include <hip/hip_runtime.h>

#define N_NODES 20000
#define N_EDGES 320000
#define NEGF   -1e30f

// d_out layout (floats):
//   out0    : [0,              N*64)
//   out1    : [N*64,           N*64 + N*192)
//   logits  : [N*256,          N*256 + E*8)

__global__ __launch_bounds__(256) void k_zero(int* __restrict__ counts)
{
    int n = blockIdx.x * 256 + threadIdx.x;
    if (n < N_NODES) counts[n] = 0;
}

__global__ __launch_bounds__(256) void k_count(
    const int* __restrict__ dst, int* __restrict__ counts)
{
    int e = blockIdx.x * 256 + threadIdx.x;
    if (e < N_EDGES) atomicAdd(&counts[dst[e]], 1);
}

// Single-block scan: 1024 threads, 20 nodes per thread, LDS Hillis-Steele.
__global__ __launch_bounds__(1024) void k_scan(
    const int* __restrict__ counts, int* __restrict__ offsets,
    int* __restrict__ cursor)
{
    __shared__ int sm[1024];
    int t = threadIdx.x;
    int base = t * 20;
    int local[20];
    int s = 0;
    if (base < N_NODES) {
#pragma unroll
        for (int i = 0; i < 20; ++i) { local[i] = counts[base + i]; s += local[i]; }
    }
    sm[t] = s; __syncthreads();
    for (int off = 1; off < 1024; off <<= 1) {
        int x = (t >= off) ? sm[t - off] : 0;
        __syncthreads();
        sm[t] += x;
        __syncthreads();
    }
    int run = sm[t] - s;                 // exclusive prefix
    if (base < N_NODES) {
#pragma unroll
        for (int i = 0; i < 20; ++i) {
            offsets[base + i] = run; cursor[base + i] = run; run += local[i];
        }
    }
    if (t == 0) offsets[N_NODES] = N_EDGES;
}

__global__ __launch_bounds__(256) void k_fill(
    const int* __restrict__ dst, int* __restrict__ cursor, int* __restrict__ bucket)
{
    int e = blockIdx.x * 256 + threadIdx.x;
    if (e >= N_EDGES) return;
    int d = dst[e];
    int pos = atomicAdd(&cursor[d], 1);
    bucket[pos] = e;
}

#define DOT4(a,b) ((a).x*(b).x + (a).y*(b).y + (a).z*(b).z + (a).w*(b).w)
#define SC4(a,s)  { (a).x*=(s); (a).y*=(s); (a).z*=(s); (a).w*=(s); }
#define FMA4(a,s,p) { (a).x += (s)*(p).x; (a).y += (s)*(p).y; (a).z += (s)*(p).z; (a).w += (s)*(p).w; }
#define RED4(a,m) { (a).x += __shfl_xor((a).x,m); (a).y += __shfl_xor((a).y,m); \
                    (a).z += __shfl_xor((a).z,m); (a).w += __shfl_xor((a).w,m); }

// One wave per node, single pass (flash-style online softmax + aggregation).
// Per 8-edge group: 16 independent float4 gathers issued up front.
__global__ __launch_bounds__(256) void k_fused(
    const float* __restrict__ v0, const float* __restrict__ v1,
    const float* __restrict__ k0, const float* __restrict__ k1,
    const float* __restrict__ q0, const float* __restrict__ q1,
    const int* __restrict__ offsets, const int* __restrict__ bucket,
    float* __restrict__ logits, float* __restrict__ out0, float* __restrict__ out1)
{
    int w = threadIdx.x >> 6;
    int l = threadIdx.x & 63;
    int node = blockIdx.x * 4 + w;          // grid covers exactly N_NODES waves

    int rs = offsets[node], re = offsets[node + 1];
    int deg = re - rs;

    int h = l & 7, slot8 = l >> 3, s2 = l >> 4, c = l & 15;
    int hv0  = c >> 1;
    int hv1a = c / 6;
    int hv1b = (c + 16) / 6;
    int hv1c = (c + 32) / 6;

    // q slices for head h, in registers (duplicated across slots; L1 merges)
    const float4* qh0 = (const float4*)(q0 + (size_t)node * 64  + h * 8);
    const float4* qh1 = (const float4*)(q1 + (size_t)node * 192 + h * 24);
    float4 Q0a = qh0[0], Q0b = qh0[1];
    float4 Q1a = qh1[0], Q1b = qh1[1], Q1c = qh1[2];
    float4 Q1d = qh1[3], Q1e = qh1[4], Q1f = qh1[5];

    // preload edge ids (deg <= 64 fast path; larger handled in-loop)
    int eL = 0;
    if (l < deg) eL = bucket[rs + l];

    float M = NEGF, S = 0.f;
    float4 a0  = {0,0,0,0}, a1a = {0,0,0,0}, a1b = {0,0,0,0}, a1c = {0,0,0,0};

    for (int base = 0; base < deg; base += 8) {
        int sA = base + slot8;
        bool okA = sA < deg;
        int iA = okA ? sA : 0;
        int eA = (iA < 64) ? __shfl(eL, iA) : bucket[rs + iA];

        int sB0 = base + s2, sB1 = base + s2 + 4;
        int iB0 = (sB0 < deg) ? sB0 : 0;
        int iB1 = (sB1 < deg) ? sB1 : 0;
        int eB0 = (iB0 < 64) ? __shfl(eL, iB0) : bucket[rs + iB0];
        int eB1 = (iB1 < 64) ? __shfl(eL, iB1) : bucket[rs + iB1];

        // ---- issue all 16 loads (8 k + 8 v float4s), all independent
        const float4* kr0 = (const float4*)(k0 + (size_t)eA * 64  + h * 8);
        const float4* kr1 = (const float4*)(k1 + (size_t)eA * 192 + h * 24);
        float4 K0a = kr0[0], K0b = kr0[1];
        float4 K1a = kr1[0], K1b = kr1[1], K1c = kr1[2];
        float4 K1d = kr1[3], K1e = kr1[4], K1f = kr1[5];

        const float4* v0A = (const float4*)(v0 + (size_t)eB0 * 64);
        const float4* v1A = (const float4*)(v1 + (size_t)eB0 * 192);
        const float4* v0B = (const float4*)(v0 + (size_t)eB1 * 64);
        const float4* v1B = (const float4*)(v1 + (size_t)eB1 * 192);
        float4 P0A = v0A[c], PaA = v1A[c], PbA = v1A[c + 16], PcA = v1A[c + 32];
        float4 P0B = v0B[c], PaB = v1B[c], PbB = v1B[c + 16], PcB = v1B[c + 32];

        // ---- logits for this group (lane = (slot8, h))
        float acc = DOT4(K0a, Q0a) + DOT4(K0b, Q0b)
                  + DOT4(K1a, Q1a) + DOT4(K1b, Q1b) + DOT4(K1c, Q1c)
                  + DOT4(K1d, Q1d) + DOT4(K1e, Q1e) + DOT4(K1f, Q1f);
        float x = okA ? acc * 0.0625f : NEGF;            // 1/sqrt(256)
        if (okA) logits[(size_t)eA * 8 + h] = x;

        // ---- online softmax update (per head; reduce over slot bits 3..5)
        float gM = x;
        gM = fmaxf(gM, __shfl_xor(gM, 8));
        gM = fmaxf(gM, __shfl_xor(gM, 16));
        gM = fmaxf(gM, __shfl_xor(gM, 32));
        float Mn = fmaxf(M, gM);
        float atil = okA ? __expf(x - Mn) : 0.f;
        float gS = atil;
        gS += __shfl_xor(gS, 8);
        gS += __shfl_xor(gS, 16);
        gS += __shfl_xor(gS, 32);
        float sc = __expf(M - Mn);                        // exp(-inf)=0 first group
        S = S * sc + gS;
        M = Mn;

        // ---- rescale accumulators (per-lane heads differ)
        float sc0 = __shfl(sc, hv0);
        float sca = __shfl(sc, hv1a);
        float scb = __shfl(sc, hv1b);
        float scc = __shfl(sc, hv1c);
        SC4(a0, sc0); SC4(a1a, sca); SC4(a1b, scb); SC4(a1c, scc);

        // ---- accumulate alpha~ * v  (alpha~ fetched cross-lane; invalid slots are 0)
        float l0A = __shfl(atil, s2 * 8 + hv0);
        float laA = __shfl(atil, s2 * 8 + hv1a);
        float lbA = __shfl(atil, s2 * 8 + hv1b);
        float lcA = __shfl(atil, s2 * 8 + hv1c);
        float l0B = __shfl(atil, (s2 + 4) * 8 + hv0);
        float laB = __shfl(atil, (s2 + 4) * 8 + hv1a);
        float lbB = __shfl(atil, (s2 + 4) * 8 + hv1b);
        float lcB = __shfl(atil, (s2 + 4) * 8 + hv1c);
        FMA4(a0, l0A, P0A); FMA4(a1a, laA, PaA); FMA4(a1b, lbA, PbA); FMA4(a1c, lcA, PcA);
        FMA4(a0, l0B, P0B); FMA4(a1a, laB, PaB); FMA4(a1b, lbB, PbB); FMA4(a1c, lcB, PcB);
    }

    float rinv = (S > 0.f) ? 1.f / S : 0.f;
    float r0 = __shfl(rinv, hv0);
    float ra = __shfl(rinv, hv1a);
    float rb = __shfl(rinv, hv1b);
    float rc = __shfl(rinv, hv1c);

    // reduce across the 4 edge sub-slots (lane bits 4..5)
    RED4(a0, 16); RED4(a0, 32);
    RED4(a1a, 16); RED4(a1a, 32);
    RED4(a1b, 16); RED4(a1b, 32);
    RED4(a1c, 16); RED4(a1c, 32);

    if (l < 16) {
        SC4(a0, r0); SC4(a1a, ra); SC4(a1b, rb); SC4(a1c, rc);
        float4* o0 = (float4*)(out0 + (size_t)node * 64);
        float4* o1 = (float4*)(out1 + (size_t)node * 192);
        o0[c]      = a0;
        o1[c]      = a1a;
        o1[c + 16] = a1b;
        o1[c + 32] = a1c;
    }
}

extern "C" void kernel_launch(void* const* d_in, const int* in_sizes, int n_in,
                              void* d_out, int out_size, void* d_ws, size_t ws_size,
                              hipStream_t stream) {
    const float* v0 = (const float*)d_in[0];
    const float* v1 = (const float*)d_in[1];
    const float* k0 = (const float*)d_in[2];
    const float* k1 = (const float*)d_in[3];
    const float* q0 = (const float*)d_in[4];
    const float* q1 = (const float*)d_in[5];
    const int*  dst = (const int*)d_in[6];

    float* out0   = (float*)d_out;
    float* out1   = out0 + (size_t)N_NODES * 64;
    float* logits = out1 + (size_t)N_NODES * 192;

    int* wsI     = (int*)d_ws;
    int* counts  = wsI;             // N
    int* offsets = wsI + 20000;     // N+1
    int* cursor  = wsI + 40064;     // N
    int* bucket  = wsI + 60192;     // E

    k_zero  <<<79,    256,  0, stream>>>(counts);
    k_count <<<1250,  256,  0, stream>>>(dst, counts);
    k_scan  <<<1,     1024, 0, stream>>>(counts, offsets, cursor);
    k_fill  <<<1250,  256,  0, stream>>>(dst, cursor, bucket);
    k_fused <<<5000,  256,  0, stream>>>(v0, v1, k0, k1, q0, q1,
                                         offsets, bucket, logits, out0, out1);
}